// Round 6
// baseline (516.597 us; speedup 1.0000x reference)
//
#include <hip/hip_runtime.h>
#include <hip/hip_cooperative_groups.h>
#include <math.h>

namespace cg = cooperative_groups;

// Problem constants
#define LSEQ   4096
#define DHALF  256
#define NSTATE 8
#define NCHUNK 256           // scan chunks
#define CLEN   16            // chunk length (NCHUNK*CLEN = 4096)
#define NSEG   8             // segments for hierarchical inter-chunk scan
#define SEGC   32            // chunks per segment

typedef __attribute__((ext_vector_type(8))) _Float16 half8;   // MFMA f16 A/B frag
typedef __attribute__((ext_vector_type(4))) _Float16 half4v;
typedef __attribute__((ext_vector_type(4))) float f32x4;

__device__ __forceinline__ float silu_f(float v)     { return v / (1.0f + __expf(-v)); }
__device__ __forceinline__ float softplus_f(float v) { return v > 20.0f ? v : log1pf(__expf(v)); }

// async global->LDS, 16B per lane; LDS dest = wave-uniform base + lane*16
__device__ __forceinline__ void gload16(const void* g, void* l) {
    __builtin_amdgcn_global_load_lds((const __attribute__((address_space(1))) void*)g,
                                     (__attribute__((address_space(3))) void*)l, 16, 0, 0);
}

// ============================================================================
// fp32 -> fp16 cast (3 tensors) + Wdt transpose + Wxp cast, one launch.
// ============================================================================
__global__ __launch_bounds__(256)
void k_cast_all(const float* __restrict__ s0, _Float16* __restrict__ d0,
                const float* __restrict__ s1, _Float16* __restrict__ d1,
                const float* __restrict__ s2, _Float16* __restrict__ d2,
                const float* __restrict__ wdt, float* __restrict__ wtT,
                const float* __restrict__ wxp, _Float16* __restrict__ wxh)
{
    int i = blockIdx.x * 256 + threadIdx.x;
    if (i >= 1310720) {
        int j = i - 1310720;
        if (j < 8192) {                       // seg3: transpose Wdt
            int d = j >> 5, k = j & 31;
            wtT[k * 256 + d] = wdt[j];
        } else {                              // seg4: cast w_xp (48x256)
            int k = j - 8192;                 // 0..12287
            wxh[k] = (_Float16)wxp[k];
        }
        return;
    }
    const float* src; _Float16* dst; int off;
    if (i < 1048576)      { src = s0; dst = d0; off = i; }
    else if (i < 1179648) { src = s1; dst = d1; off = i - 1048576; }
    else                  { src = s2; dst = d2; off = i - 1179648; }
    float4 v = ((const float4*)src)[off];
    half4v h;
    h.x = (_Float16)v.x; h.y = (_Float16)v.y; h.z = (_Float16)v.z; h.w = (_Float16)v.w;
    ((half4v*)dst)[off] = h;
}

// ============================================================================
// MFMA bt-GEMM core (C = A * B^T), fp16, 128(M) x 64(N) tile / block,
// 4 waves each 64x32 via 4x2 16x16x32 MFMAs. Used by out_proj (N=512 is
// parallelism-constrained: 64x64/wave would leave 1 block/CU).
// ============================================================================
#define GEMM_CORE_F16(K_, M0_, N0_)                                                     \
    const int t = threadIdx.x;                                                          \
    const int wv = t >> 6, lane = t & 63;                                               \
    const int wm = (wv & 1) * 64, wn = (wv >> 1) * 32;                                  \
    const int lm = lane & 15, q = lane >> 4;                                            \
    const int M0 = (M0_), N0 = (N0_);                                                   \
    const int lr = lane >> 3;                  /* row within 8-row group */             \
    const int cc = (lane & 7) ^ lr;            /* swizzled source chunk  */             \
    const size_t gA = (size_t)(M0 + wv * 32 + lr) * K_ + cc * 8;                        \
    const size_t gB = (size_t)(N0 + wv * 16 + lr) * K_ + cc * 8;                        \
    f32x4 acc[4][2] = {};                                                               \
    for (int kb = 0; kb < K_; kb += 64) {                                               \
        __syncthreads();                                                                \
        gload16(Af + gA + kb,               &sA[(wv * 32 +  0) * 64]);                  \
        gload16(Af + gA + (size_t)8  * K_ + kb, &sA[(wv * 32 +  8) * 64]);              \
        gload16(Af + gA + (size_t)16 * K_ + kb, &sA[(wv * 32 + 16) * 64]);              \
        gload16(Af + gA + (size_t)24 * K_ + kb, &sA[(wv * 32 + 24) * 64]);              \
        gload16(Bf + gB + kb,               &sB[(wv * 16 +  0) * 64]);                  \
        gload16(Bf + gB + (size_t)8  * K_ + kb, &sB[(wv * 16 +  8) * 64]);              \
        __syncthreads();                                                                \
        _Pragma("unroll")                                                               \
        for (int kk = 0; kk < 2; ++kk) {                                                \
            const int cpos = (((kk << 2) + q) ^ (lm & 7)) * 8;                          \
            half8 a[4], b[2];                                                           \
            _Pragma("unroll")                                                           \
            for (int i = 0; i < 4; ++i)                                                 \
                a[i] = *(const half8*)&sA[(wm + i * 16 + lm) * 64 + cpos];              \
            _Pragma("unroll")                                                           \
            for (int j = 0; j < 2; ++j)                                                 \
                b[j] = *(const half8*)&sB[(wn + j * 16 + lm) * 64 + cpos];              \
            _Pragma("unroll")                                                           \
            for (int i = 0; i < 4; ++i)                                                 \
                _Pragma("unroll")                                                       \
                for (int j = 0; j < 2; ++j)                                             \
                    acc[i][j] = __builtin_amdgcn_mfma_f32_16x16x32_f16(a[i], b[j], acc[i][j], 0, 0, 0); \
        }                                                                               \
    }

// ============================================================================
// in_proj: M=8192 (b,l), N=1024 (e), K=512. 128x128 tile, 4 waves each 64x64
// (acc[4][4]). Grid 512 = 2 blocks/CU. Epilogue folds split+reverse; fp16 out.
// ============================================================================
__global__ __launch_bounds__(256)
void k_in_proj_mfma(const _Float16* __restrict__ Af, const _Float16* __restrict__ Bf,
                    _Float16* __restrict__ xh, _Float16* __restrict__ zh)
{
    __shared__ _Float16 sA[128 * 64], sB[128 * 64];
    const int K_ = 512;
    const int t = threadIdx.x;
    const int wv = t >> 6, lane = t & 63;
    const int wm = (wv & 1) * 64, wn = (wv >> 1) * 64;
    const int lm = lane & 15, q = lane >> 4;
    const int M0 = (int)(blockIdx.x & 63) * 128;
    const int N0 = (int)(blockIdx.x >> 6) * 128;
    const int lr = lane >> 3;
    const int cc = (lane & 7) ^ lr;
    const size_t gA = (size_t)(M0 + wv * 32 + lr) * K_ + cc * 8;
    const size_t gB = (size_t)(N0 + wv * 32 + lr) * K_ + cc * 8;
    f32x4 acc[4][4] = {};
    for (int kb = 0; kb < K_; kb += 64) {
        __syncthreads();
        gload16(Af + gA + kb,                   &sA[(wv * 32 +  0) * 64]);
        gload16(Af + gA + (size_t)8  * K_ + kb, &sA[(wv * 32 +  8) * 64]);
        gload16(Af + gA + (size_t)16 * K_ + kb, &sA[(wv * 32 + 16) * 64]);
        gload16(Af + gA + (size_t)24 * K_ + kb, &sA[(wv * 32 + 24) * 64]);
        gload16(Bf + gB + kb,                   &sB[(wv * 32 +  0) * 64]);
        gload16(Bf + gB + (size_t)8  * K_ + kb, &sB[(wv * 32 +  8) * 64]);
        gload16(Bf + gB + (size_t)16 * K_ + kb, &sB[(wv * 32 + 16) * 64]);
        gload16(Bf + gB + (size_t)24 * K_ + kb, &sB[(wv * 32 + 24) * 64]);
        __syncthreads();
#pragma unroll
        for (int kk = 0; kk < 2; ++kk) {
            const int cpos = (((kk << 2) + q) ^ (lm & 7)) * 8;
            half8 a[4], b[4];
#pragma unroll
            for (int i = 0; i < 4; ++i)
                a[i] = *(const half8*)&sA[(wm + i * 16 + lm) * 64 + cpos];
#pragma unroll
            for (int j = 0; j < 4; ++j)
                b[j] = *(const half8*)&sB[(wn + j * 16 + lm) * 64 + cpos];
#pragma unroll
            for (int i = 0; i < 4; ++i)
#pragma unroll
                for (int j = 0; j < 4; ++j)
                    acc[i][j] = __builtin_amdgcn_mfma_f32_16x16x32_f16(a[i], b[j], acc[i][j], 0, 0, 0);
        }
    }
    const int region = N0 >> 8;               // 0..3 uniform per block (128|256)
    const int eobase = (N0 & 255) + wn;
    _Float16* basep = ((region & 1) == 0) ? xh : zh;
#pragma unroll
    for (int i = 0; i < 4; ++i) {
#pragma unroll
        for (int r = 0; r < 4; ++r) {
            int m = M0 + wm + i * 16 + q * 4 + r;
            int b = m >> 12, l = m & 4095;
            size_t rowoff = (region < 2)
                ? ((size_t)b * 4096 + l) * 256
                : ((size_t)(b + 2) * 4096 + (4095 - l)) * 256;
#pragma unroll
            for (int j = 0; j < 4; ++j)
                basep[rowoff + eobase + j * 16 + lm] = (_Float16)acc[i][j][r];
        }
    }
}

// out_proj: M=8192 (b,l), N=512 (o), K=1024.
__global__ __launch_bounds__(256)
void k_out_proj_mfma(const _Float16* __restrict__ Af, const _Float16* __restrict__ Bf,
                     float* __restrict__ out)
{
    __shared__ _Float16 sA[128 * 64], sB[64 * 64];
    GEMM_CORE_F16(1024, (int)(blockIdx.x & 63) * 128, (int)(blockIdx.x >> 6) * 64)
#pragma unroll
    for (int i = 0; i < 4; ++i) {
#pragma unroll
        for (int r = 0; r < 4; ++r) {
            size_t m = (size_t)(M0 + wm + i * 16 + q * 4 + r);
#pragma unroll
            for (int j = 0; j < 2; ++j)
                out[m * 512 + N0 + wn + j * 16 + lm] = acc[i][j][r];
        }
    }
}

// ============================================================================
// conv_x (dil 8 -> u fp16) and conv_z (dil 1 -> ybuf fp16, un-reversal folded)
// merged: fp16 in, fp32 math, fp16 out. 8 channels / thread (half8 = 16B).
// ============================================================================
__global__ __launch_bounds__(256)
void k_conv_both(const _Float16* __restrict__ xh, const _Float16* __restrict__ zh,
                 const float* __restrict__ wx, const float* __restrict__ wz,
                 _Float16* __restrict__ uh, _Float16* __restrict__ yb)
{
    int gid = blockIdx.x * 256 + threadIdx.x;
    const bool isZ = gid >= 524288;
    int idx = gid & 524287;
    int b = idx >> 17, rem = idx & 131071;
    int l = rem >> 5, d0 = (rem & 31) * 8;
    const _Float16* base = (isZ ? zh : xh) + (size_t)b * 4096 * 256 + d0;
    const float* w = (isZ ? wz : wx) + d0 * 4;
    const int dil = isZ ? 1 : 8;
    float wt[8][4];
#pragma unroll
    for (int j = 0; j < 8; ++j) {
        float4 wv = *(const float4*)(w + j * 4);
        wt[j][0] = wv.x; wt[j][1] = wv.y; wt[j][2] = wv.z; wt[j][3] = wv.w;
    }
    float acc[8];
    half8 v = *(const half8*)(base + (size_t)l * 256);
#pragma unroll
    for (int j = 0; j < 8; ++j) acc[j] = wt[j][3] * (float)v[j];
#pragma unroll
    for (int tp = 1; tp <= 3; ++tp) {
        int ls = l - tp * dil;
        if (ls >= 0) {
            half8 vv = *(const half8*)(base + (size_t)ls * 256);
#pragma unroll
            for (int j = 0; j < 8; ++j) acc[j] += wt[j][3 - tp] * (float)vv[j];
        }
    }
    half8 o;
#pragma unroll
    for (int j = 0; j < 8; ++j) o[j] = (_Float16)silu_f(acc[j]);
    if (!isZ) {
        *(half8*)(uh + ((size_t)b * 4096 + l) * 256 + d0) = o;
    } else {
        size_t oidx = (b < 2) ? ((size_t)b * 4096 + l) * 1024 + 256 + d0
                              : ((size_t)(b - 2) * 4096 + (4095 - l)) * 1024 + 768 + d0;
        *(half8*)(yb + oidx) = o;
    }
}

// ============================================================================
// x_proj as MFMA bt-GEMM: C[m][e] = sum_k u[m][k] Wx[e][k].
// M=16384, N=48, K=256. BM=64, full K staged at once, ONE barrier.
// ============================================================================
__global__ __launch_bounds__(256)
void k_xproj_mfma(const _Float16* __restrict__ Af, const _Float16* __restrict__ Bf,
                  float* __restrict__ xdbl)
{
    __shared__ _Float16 sA[4 * 64 * 64];   // 32KB: [slab][64 rows][64]
    __shared__ _Float16 sB[4 * 48 * 64];   // 24KB: [slab][48 rows][64]
    const int t = threadIdx.x;
    const int wv = t >> 6, lane = t & 63;
    const int lm = lane & 15, q = lane >> 4;
    const int lr = lane >> 3;
    const int cc = (lane & 7) ^ lr;        // swizzled source chunk
    const int m0 = blockIdx.x * 64;
    const size_t gA = (size_t)(m0 + wv * 16 + lr) * 256 + cc * 8;
    const size_t gB = (size_t)(wv * 16 + lr) * 256 + cc * 8;
#pragma unroll
    for (int s = 0; s < 4; ++s) {
        gload16(Af + gA + s * 64,                   &sA[s * 4096 + (wv * 16 + 0) * 64]);
        gload16(Af + gA + (size_t)8 * 256 + s * 64, &sA[s * 4096 + (wv * 16 + 8) * 64]);
        if (wv < 3) {
            gload16(Bf + gB + s * 64,                   &sB[s * 3072 + (wv * 16 + 0) * 64]);
            gload16(Bf + gB + (size_t)8 * 256 + s * 64, &sB[s * 3072 + (wv * 16 + 8) * 64]);
        }
    }
    __syncthreads();
    f32x4 acc[3] = {};
#pragma unroll
    for (int s = 0; s < 4; ++s) {
#pragma unroll
        for (int kk = 0; kk < 2; ++kk) {
            const int cpos = (((kk << 2) + q) ^ (lm & 7)) * 8;
            half8 a = *(const half8*)&sA[s * 4096 + (wv * 16 + lm) * 64 + cpos];
#pragma unroll
            for (int j = 0; j < 3; ++j) {
                half8 b = *(const half8*)&sB[s * 3072 + (j * 16 + lm) * 64 + cpos];
                acc[j] = __builtin_amdgcn_mfma_f32_16x16x32_f16(a, b, acc[j], 0, 0, 0);
            }
        }
    }
#pragma unroll
    for (int j = 0; j < 3; ++j)
#pragma unroll
        for (int r = 0; r < 4; ++r)
            xdbl[(size_t)(m0 + wv * 16 + q * 4 + r) * 48 + j * 16 + lm] = acc[j][r];
}

// ============================================================================
// FUSED selective scan (scan1 + scan2a + scan3) -- one cooperative kernel,
// 1024 blocks x 256 thr = 4 blocks/CU (co-resident; LDS 13.3KB, VGPR<=128 via
// launch_bounds). Phase A = intra-chunk aggregates; grid.sync; Phase B =
// hierarchical inter-chunk (blocks 0..255); grid.sync; Phase C = final pass.
// C reuses A's registers (w, a, bias, dlt[16]) and LDS (Bsh/Csh): kills the
// 2nd delta dot-product, the 2nd Xs/WT staging, and 2 kernel launches.
// ============================================================================
__global__ __launch_bounds__(256, 4)
void k_scan_fused(const _Float16* __restrict__ uh, const float* __restrict__ xdbl,
                  const float* __restrict__ WT, const float* __restrict__ bdt,
                  const float* __restrict__ A_log, const float* __restrict__ Dp,
                  float* __restrict__ chS, float* __restrict__ chB,
                  float* __restrict__ hloc, float* __restrict__ scum,
                  float* __restrict__ segS, float* __restrict__ segB,
                  _Float16* __restrict__ yb)
{
    cg::grid_group grid = cg::this_grid();
    __shared__ float Xs[CLEN][36];
    __shared__ float Bsh[8][CLEN];
    __shared__ float Csh[8][CLEN];
    const int bid = blockIdx.x;
    const int b = bid >> 8;
    const int c = bid & 255;
    const int d = threadIdx.x;
    const int l0 = c * CLEN;
    const size_t mbase = (size_t)b * 4096 + l0;
    if (threadIdx.x < 128) {               // 16 rows x 32 dtr cols = 128 float4
        int r = threadIdx.x >> 3, cc2 = (threadIdx.x & 7) * 4;
        *(float4*)&Xs[r][cc2] = *(const float4*)(xdbl + (mbase + r) * 48 + cc2);
    } else {
        int s = threadIdx.x - 128;
        int i = s >> 3, n = s & 7;
        Bsh[n][i] = xdbl[(mbase + i) * 48 + 32 + n];
        Csh[n][i] = xdbl[(mbase + i) * 48 + 40 + n];
    }
    float w[32];
#pragma unroll
    for (int k = 0; k < 32; ++k) w[k] = WT[k * 256 + d];
    const float bias = bdt[d];
    float a[8];
#pragma unroll
    for (int n = 0; n < 8; ++n) a[n] = -__expf(A_log[d * 8 + n]);
    const float Dd = Dp[d];
    __syncthreads();
    const _Float16* up = uh + mbase * 256 + d;

    // ---- Phase A: delta + intra-chunk recurrence (h0 = 0) -> aggregates ----
    float dlt[CLEN];
    {
        float h[8];
#pragma unroll
        for (int n = 0; n < 8; ++n) h[n] = 0.0f;
        float S = 0.0f;
#pragma unroll
        for (int i = 0; i < CLEN; ++i) {
            const float4* xr = (const float4*)&Xs[i][0];
            float accd = bias;
#pragma unroll
            for (int j = 0; j < 8; ++j) {
                float4 xv = xr[j];
                accd = fmaf(xv.x, w[4*j+0], accd);
                accd = fmaf(xv.y, w[4*j+1], accd);
                accd = fmaf(xv.z, w[4*j+2], accd);
                accd = fmaf(xv.w, w[4*j+3], accd);
            }
            dlt[i] = softplus_f(accd);
            float u  = (float)up[(size_t)i * 256];
            float du = dlt[i] * u;
            S += dlt[i];
#pragma unroll
            for (int n = 0; n < 8; ++n) {
                float dA = __expf(dlt[i] * a[n]);
                h[n] = dA * h[n] + du * Bsh[n][i];
            }
        }
        chS[((size_t)b * NCHUNK + c) * 256 + d] = S;
#pragma unroll
        for (int n = 0; n < 8; ++n)
            chB[(((size_t)b * NCHUNK + c) * 8 + n) * 256 + d] = h[n];
    }
    grid.sync();

    // ---- Phase B: hierarchical inter-chunk (blocks 0..255 only) ----
    if (bid < 256) {
        const int bb  = bid >> 6;
        const int n   = (bid >> 3) & 7;
        const int seg = bid & 7;
        const int c0  = seg * SEGC;
        const float aa = -__expf(A_log[d * 8 + n]);
        float h = 0.0f, Sc = 0.0f;
        for (int jb = 0; jb < SEGC; jb += 8) {
            float S[8], Bc[8];
#pragma unroll
            for (int j = 0; j < 8; ++j) {
                int c2 = c0 + jb + j;
                S[j]  = chS[((size_t)bb * NCHUNK + c2) * 256 + d];
                Bc[j] = chB[(((size_t)bb * NCHUNK + c2) * 8 + n) * 256 + d];
            }
#pragma unroll
            for (int j = 0; j < 8; ++j) {
                int c2 = c0 + jb + j;
                hloc[(((size_t)bb * NCHUNK + c2) * 8 + n) * 256 + d] = h;
                if (n == 0) scum[((size_t)bb * NCHUNK + c2) * 256 + d] = Sc;
                h  = __expf(aa * S[j]) * h + Bc[j];
                Sc += S[j];
            }
        }
        segB[(((size_t)bb * NSEG + seg) * 8 + n) * 256 + d] = h;
        if (n == 0) segS[((size_t)bb * NSEG + seg) * 256 + d] = Sc;
    }
    grid.sync();

    // ---- Phase C: compose h0, final pass with cached dlt/Bsh/Csh ----
    {
        const int seg = c >> 5;
        float hs_[8];
#pragma unroll
        for (int n = 0; n < 8; ++n) hs_[n] = 0.0f;
        for (int s = 0; s < seg; ++s) {
            float Es = segS[((size_t)b * NSEG + s) * 256 + d];
#pragma unroll
            for (int n = 0; n < 8; ++n)
                hs_[n] = __expf(a[n] * Es) * hs_[n]
                       + segB[(((size_t)b * NSEG + s) * 8 + n) * 256 + d];
        }
        const float Sc = scum[((size_t)b * NCHUNK + c) * 256 + d];
        float h[8];
#pragma unroll
        for (int n = 0; n < 8; ++n)
            h[n] = __expf(a[n] * Sc) * hs_[n]
                 + hloc[(((size_t)b * NCHUNK + c) * 8 + n) * 256 + d];
#pragma unroll
        for (int i = 0; i < CLEN; ++i) {
            float u  = (float)up[(size_t)i * 256];
            float du = dlt[i] * u;
            float y  = u * Dd;
#pragma unroll
            for (int n = 0; n < 8; ++n) {
                float dA = __expf(dlt[i] * a[n]);
                h[n] = dA * h[n] + du * Bsh[n][i];
                y += h[n] * Csh[n][i];
            }
            int l = l0 + i;
            size_t oidx = (b < 2) ? ((size_t)b * 4096 + l) * 1024 + d
                                  : ((size_t)(b - 2) * 4096 + (4095 - l)) * 1024 + 512 + d;
            yb[oidx] = (_Float16)y;
        }
    }
}

// ============================================================================
// Fallback split-scan kernels (used only if cooperative launch is refused).
// ============================================================================
__global__ __launch_bounds__(256)
void k_scan1(const _Float16* __restrict__ uh, const float* __restrict__ xdbl,
             const float* __restrict__ WT, const float* __restrict__ bdt,
             const float* __restrict__ A_log,
             float* __restrict__ chS, float* __restrict__ chB)
{
    __shared__ float Xs[CLEN][36];
    __shared__ float Bsh[8][CLEN];
    const int b = blockIdx.x >> 8;
    const int c = blockIdx.x & 255;
    const int d = threadIdx.x;
    const int l0 = c * CLEN;
    const size_t mbase = (size_t)b * 4096 + l0;
    if (threadIdx.x < 128) {
        int r = threadIdx.x >> 3, cc = (threadIdx.x & 7) * 4;
        *(float4*)&Xs[r][cc] = *(const float4*)(xdbl + (mbase + r) * 48 + cc);
    } else {
        int s = threadIdx.x - 128;
        int i = s >> 3, n = s & 7;
        Bsh[n][i] = xdbl[(mbase + i) * 48 + 32 + n];
    }
    float w[32];
#pragma unroll
    for (int k = 0; k < 32; ++k) w[k] = WT[k * 256 + d];
    const float bias = bdt[d];
    float a[8], h[8];
#pragma unroll
    for (int n = 0; n < 8; ++n) { a[n] = -__expf(A_log[d * 8 + n]); h[n] = 0.0f; }
    float S = 0.0f;
    __syncthreads();
    const _Float16* up = uh + mbase * 256 + d;
    for (int i = 0; i < CLEN; ++i) {
        const float4* xr = (const float4*)&Xs[i][0];
        float accd = bias;
#pragma unroll
        for (int j = 0; j < 8; ++j) {
            float4 xv = xr[j];
            accd = fmaf(xv.x, w[4*j+0], accd);
            accd = fmaf(xv.y, w[4*j+1], accd);
            accd = fmaf(xv.z, w[4*j+2], accd);
            accd = fmaf(xv.w, w[4*j+3], accd);
        }
        float dlt = softplus_f(accd);
        float u   = (float)up[(size_t)i * 256];
        float du  = dlt * u;
        S += dlt;
#pragma unroll
        for (int n = 0; n < 8; ++n) {
            float dA = __expf(dlt * a[n]);
            h[n] = dA * h[n] + du * Bsh[n][i];
        }
    }
    chS[((size_t)b * NCHUNK + c) * 256 + d] = S;
#pragma unroll
    for (int n = 0; n < 8; ++n)
        chB[(((size_t)b * NCHUNK + c) * 8 + n) * 256 + d] = h[n];
}

__global__ __launch_bounds__(256)
void k_scan2a(const float* __restrict__ chS, const float* __restrict__ chB,
              const float* __restrict__ A_log,
              float* __restrict__ hloc, float* __restrict__ scum,
              float* __restrict__ segS, float* __restrict__ segB)
{
    const int b   = blockIdx.x >> 6;
    const int n   = (blockIdx.x >> 3) & 7;
    const int seg = blockIdx.x & 7;
    const int d   = threadIdx.x;
    const int c0  = seg * SEGC;
    const float a = -__expf(A_log[d * 8 + n]);
    float h = 0.0f, Sc = 0.0f;
    for (int jb = 0; jb < SEGC; jb += 16) {
        float S[16], Bc[16];
#pragma unroll
        for (int j = 0; j < 16; ++j) {
            int c = c0 + jb + j;
            S[j]  = chS[((size_t)b * NCHUNK + c) * 256 + d];
            Bc[j] = chB[(((size_t)b * NCHUNK + c) * 8 + n) * 256 + d];
        }
#pragma unroll
        for (int j = 0; j < 16; ++j) {
            int c = c0 + jb + j;
            hloc[(((size_t)b * NCHUNK + c) * 8 + n) * 256 + d] = h;
            if (n == 0) scum[((size_t)b * NCHUNK + c) * 256 + d] = Sc;
            h  = __expf(a * S[j]) * h + Bc[j];
            Sc += S[j];
        }
    }
    segB[(((size_t)b * NSEG + seg) * 8 + n) * 256 + d] = h;
    if (n == 0) segS[((size_t)b * NSEG + seg) * 256 + d] = Sc;
}

__global__ __launch_bounds__(256)
void k_scan3(const _Float16* __restrict__ uh, const float* __restrict__ xdbl,
             const float* __restrict__ WT, const float* __restrict__ bdt,
             const float* __restrict__ A_log, const float* __restrict__ Dp,
             const float* __restrict__ hloc, const float* __restrict__ scum,
             const float* __restrict__ segS, const float* __restrict__ segB,
             _Float16* __restrict__ yb)
{
    __shared__ float Xs[CLEN][36];
    __shared__ float Bsh[8][CLEN];
    __shared__ float Csh[8][CLEN];
    const int b = blockIdx.x >> 8;
    const int c = blockIdx.x & 255;
    const int seg = c >> 5;
    const int d = threadIdx.x;
    const int l0 = c * CLEN;
    const size_t mbase = (size_t)b * 4096 + l0;
    if (threadIdx.x < 128) {
        int r = threadIdx.x >> 3, cc = (threadIdx.x & 7) * 4;
        *(float4*)&Xs[r][cc] = *(const float4*)(xdbl + (mbase + r) * 48 + cc);
    } else {
        int s = threadIdx.x - 128;
        int i = s >> 3, n = s & 7;
        Bsh[n][i] = xdbl[(mbase + i) * 48 + 32 + n];
        Csh[n][i] = xdbl[(mbase + i) * 48 + 40 + n];
    }
    float w[32];
#pragma unroll
    for (int k = 0; k < 32; ++k) w[k] = WT[k * 256 + d];
    const float bias = bdt[d];
    float a[8];
#pragma unroll
    for (int n = 0; n < 8; ++n) a[n] = -__expf(A_log[d * 8 + n]);
    float hs_[8];
#pragma unroll
    for (int n = 0; n < 8; ++n) hs_[n] = 0.0f;
    for (int s = 0; s < seg; ++s) {
        float Es = segS[((size_t)b * NSEG + s) * 256 + d];
#pragma unroll
        for (int n = 0; n < 8; ++n)
            hs_[n] = __expf(a[n] * Es) * hs_[n]
                   + segB[(((size_t)b * NSEG + s) * 8 + n) * 256 + d];
    }
    const float Sc = scum[((size_t)b * NCHUNK + c) * 256 + d];
    float h[8];
#pragma unroll
    for (int n = 0; n < 8; ++n)
        h[n] = __expf(a[n] * Sc) * hs_[n]
             + hloc[(((size_t)b * NCHUNK + c) * 8 + n) * 256 + d];
    const float Dd = Dp[d];
    __syncthreads();
    const _Float16* up = uh + mbase * 256 + d;
    for (int i = 0; i < CLEN; ++i) {
        const float4* xr = (const float4*)&Xs[i][0];
        float accd = bias;
#pragma unroll
        for (int j = 0; j < 8; ++j) {
            float4 xv = xr[j];
            accd = fmaf(xv.x, w[4*j+0], accd);
            accd = fmaf(xv.y, w[4*j+1], accd);
            accd = fmaf(xv.z, w[4*j+2], accd);
            accd = fmaf(xv.w, w[4*j+3], accd);
        }
        float dlt = softplus_f(accd);
        float u   = (float)up[(size_t)i * 256];
        float du  = dlt * u;
        float y   = u * Dd;
#pragma unroll
        for (int n = 0; n < 8; ++n) {
            float dA = __expf(dlt * a[n]);
            h[n] = dA * h[n] + du * Bsh[n][i];
            y += h[n] * Csh[n][i];
        }
        int l = l0 + i;
        size_t oidx = (b < 2) ? ((size_t)b * 4096 + l) * 1024 + d
                              : ((size_t)(b - 2) * 4096 + (4095 - l)) * 1024 + 512 + d;
        yb[oidx] = (_Float16)y;
    }
}

// ============================================================================
extern "C" void kernel_launch(void* const* d_in, const int* in_sizes, int n_in,
                              void* d_out, int out_size, void* d_ws, size_t ws_size,
                              hipStream_t stream)
{
    const float* hs    = (const float*)d_in[0];   // (2,4096,512)
    const float* w_in  = (const float*)d_in[1];   // (1024,512)
    const float* w_xp  = (const float*)d_in[2];   // (48,256)
    const float* w_dt  = (const float*)d_in[3];   // (256,32)
    const float* b_dt  = (const float*)d_in[4];   // (256,)
    const float* A_log = (const float*)d_in[5];   // (256,8)
    const float* Dpar  = (const float*)d_in[6];   // (256,)
    const float* w_cx  = (const float*)d_in[7];   // (256,1,4)
    const float* w_cz  = (const float*)d_in[8];   // (256,1,4)
    const float* w_out = (const float*)d_in[9];   // (512,1024)
    float* out = (float*)d_out;                   // (2,4096,512)

    float* ws   = (float*)d_ws;
    float*    xdbl = ws;                            // [4][4096][48]          786432 f
    float*    chS  = xdbl + 786432;                 // [4][256][256]          262144 f
    float*    chB  = chS  + 262144;                 // [4][256][8][256]      2097152 f
    float*    hloc = chB  + 2097152;                // [4][256][8][256]      2097152 f
    float*    scum = hloc + 2097152;                // [4][256][256]          262144 f
    float*    segS = scum + 262144;                 // [4][8][256]              8192 f
    float*    segB = segS + 8192;                   // [4][8][8][256]          65536 f
    float*    wtT  = segB + 65536;                  // [32][256] Wdt^T          8192 f
    _Float16* xh   = (_Float16*)(wtT + 8192);       // [4][4096][256] fp16
    _Float16* zh   = xh + 4194304;                  // [4][4096][256] fp16
    _Float16* uh   = zh + 4194304;                  // [4][4096][256] fp16
    _Float16* hsf  = uh + 4194304;                  // [8192][512] fp16
    _Float16* wif  = hsf + 4194304;                 // [1024][512] fp16
    _Float16* wof  = wif + 524288;                  // [512][1024] fp16
    _Float16* wxh  = wof + 524288;                  // [48][256] fp16
    _Float16* ybf  = wxh + 12288;                   // [2][4096][1024] fp16

    k_cast_all     <<<5200, 256, 0, stream>>>(hs, hsf, w_in, wif, w_out, wof,
                                              w_dt, wtT, w_xp, wxh);
    k_in_proj_mfma <<<512,  256, 0, stream>>>(hsf, wif, xh, zh);
    k_conv_both    <<<4096, 256, 0, stream>>>(xh, zh, w_cx, w_cz, uh, ybf);
    k_xproj_mfma   <<<256,  256, 0, stream>>>(uh, wxh, xdbl);

    // fused cooperative scan; fall back to split kernels if refused
    {
        const _Float16* uh_c = uh;
        const float *xdbl_c = xdbl, *wtT_c = wtT, *bdt_c = b_dt,
                    *alog_c = A_log, *dp_c = Dpar;
        void* args[] = { (void*)&uh_c, (void*)&xdbl_c, (void*)&wtT_c, (void*)&bdt_c,
                         (void*)&alog_c, (void*)&dp_c,
                         (void*)&chS, (void*)&chB, (void*)&hloc, (void*)&scum,
                         (void*)&segS, (void*)&segB, (void*)&ybf };
        hipError_t cerr = hipLaunchCooperativeKernel(
            reinterpret_cast<void*>(k_scan_fused),
            dim3(1024), dim3(256), args, 0, stream);
        if (cerr != hipSuccess) {
            k_scan1 <<<1024, 256, 0, stream>>>(uh, xdbl, wtT, b_dt, A_log, chS, chB);
            k_scan2a<<<256,  256, 0, stream>>>(chS, chB, A_log, hloc, scum, segS, segB);
            k_scan3 <<<1024, 256, 0, stream>>>(uh, xdbl, wtT, b_dt, A_log, Dpar,
                                               hloc, scum, segS, segB, ybf);
        }
    }

    k_out_proj_mfma<<<512,  256, 0, stream>>>(ybf, wof, out);
}

// Round 9
// 212.784 us; speedup vs baseline: 2.4278x; 2.4278x over previous
//
#include <hip/hip_runtime.h>
#include <math.h>

// Problem constants
#define LSEQ   4096
#define DHALF  256
#define NSTATE 8
#define NCHUNK 256           // scan chunks
#define CLEN   16            // chunk length (NCHUNK*CLEN = 4096)
#define NSEG   8             // segments for hierarchical inter-chunk scan
#define SEGC   32            // chunks per segment

typedef __attribute__((ext_vector_type(8))) _Float16 half8;   // MFMA f16 A/B frag
typedef __attribute__((ext_vector_type(4))) _Float16 half4v;
typedef __attribute__((ext_vector_type(4))) float f32x4;

__device__ __forceinline__ float silu_f(float v)     { return v / (1.0f + __expf(-v)); }
__device__ __forceinline__ float softplus_f(float v) { return v > 20.0f ? v : log1pf(__expf(v)); }

// async global->LDS, 16B per lane; LDS dest = wave-uniform base + lane*16
__device__ __forceinline__ void gload16(const void* g, void* l) {
    __builtin_amdgcn_global_load_lds((const __attribute__((address_space(1))) void*)g,
                                     (__attribute__((address_space(3))) void*)l, 16, 0, 0);
}

// ============================================================================
// fp32 -> fp16 cast (3 tensors) + Wdt transpose + Wxp cast, one launch.
// ============================================================================
__global__ __launch_bounds__(256)
void k_cast_all(const float* __restrict__ s0, _Float16* __restrict__ d0,
                const float* __restrict__ s1, _Float16* __restrict__ d1,
                const float* __restrict__ s2, _Float16* __restrict__ d2,
                const float* __restrict__ wdt, float* __restrict__ wtT,
                const float* __restrict__ wxp, _Float16* __restrict__ wxh)
{
    int i = blockIdx.x * 256 + threadIdx.x;
    if (i >= 1310720) {
        int j = i - 1310720;
        if (j < 8192) {                       // seg3: transpose Wdt
            int d = j >> 5, k = j & 31;
            wtT[k * 256 + d] = wdt[j];
        } else {                              // seg4: cast w_xp (48x256)
            int k = j - 8192;                 // 0..12287
            wxh[k] = (_Float16)wxp[k];
        }
        return;
    }
    const float* src; _Float16* dst; int off;
    if (i < 1048576)      { src = s0; dst = d0; off = i; }
    else if (i < 1179648) { src = s1; dst = d1; off = i - 1048576; }
    else                  { src = s2; dst = d2; off = i - 1179648; }
    float4 v = ((const float4*)src)[off];
    half4v h;
    h.x = (_Float16)v.x; h.y = (_Float16)v.y; h.z = (_Float16)v.z; h.w = (_Float16)v.w;
    ((half4v*)dst)[off] = h;
}

// ============================================================================
// in_proj: M=8192 (b,l), N=1024 (e), K=512. 128x128 tile, 4 waves each 64x64
// (acc[4][4]). BK=128 via TWO 64-wide slabs per barrier-pair (identical
// per-slab swizzle as the proven BK=64 core) -- barrier-pairs 8 -> 4, the
// vmcnt(0)+barrier drain amortizes over 64 MFMA/wave instead of 32.
// LDS 64 KB; grid 512 = 2 blocks/CU. Epilogue folds split+reverse; fp16 out.
// ============================================================================
__global__ __launch_bounds__(256)
void k_in_proj_mfma(const _Float16* __restrict__ Af, const _Float16* __restrict__ Bf,
                    _Float16* __restrict__ xh, _Float16* __restrict__ zh)
{
    __shared__ _Float16 sA[2 * 128 * 64], sB[2 * 128 * 64];   // 32KB + 32KB
    const int K_ = 512;
    const int t = threadIdx.x;
    const int wv = t >> 6, lane = t & 63;
    const int wm = (wv & 1) * 64, wn = (wv >> 1) * 64;
    const int lm = lane & 15, q = lane >> 4;
    const int M0 = (int)(blockIdx.x & 63) * 128;
    const int N0 = (int)(blockIdx.x >> 6) * 128;
    const int lr = lane >> 3;
    const int cc = (lane & 7) ^ lr;        // swizzled source chunk
    const size_t gA = (size_t)(M0 + wv * 32 + lr) * K_ + cc * 8;
    const size_t gB = (size_t)(N0 + wv * 32 + lr) * K_ + cc * 8;
    f32x4 acc[4][4] = {};
    for (int kb = 0; kb < K_; kb += 128) {
        __syncthreads();
#pragma unroll
        for (int s = 0; s < 2; ++s) {
            const int ko = kb + s * 64;
            const int lo = s * 8192;
            gload16(Af + gA + ko,                   &sA[lo + (wv * 32 +  0) * 64]);
            gload16(Af + gA + (size_t)8  * K_ + ko, &sA[lo + (wv * 32 +  8) * 64]);
            gload16(Af + gA + (size_t)16 * K_ + ko, &sA[lo + (wv * 32 + 16) * 64]);
            gload16(Af + gA + (size_t)24 * K_ + ko, &sA[lo + (wv * 32 + 24) * 64]);
            gload16(Bf + gB + ko,                   &sB[lo + (wv * 32 +  0) * 64]);
            gload16(Bf + gB + (size_t)8  * K_ + ko, &sB[lo + (wv * 32 +  8) * 64]);
            gload16(Bf + gB + (size_t)16 * K_ + ko, &sB[lo + (wv * 32 + 16) * 64]);
            gload16(Bf + gB + (size_t)24 * K_ + ko, &sB[lo + (wv * 32 + 24) * 64]);
        }
        __syncthreads();
#pragma unroll
        for (int s = 0; s < 2; ++s) {
            const int lo = s * 8192;
#pragma unroll
            for (int kk = 0; kk < 2; ++kk) {
                const int cpos = (((kk << 2) + q) ^ (lm & 7)) * 8;
                half8 a[4], b[4];
#pragma unroll
                for (int i = 0; i < 4; ++i)
                    a[i] = *(const half8*)&sA[lo + (wm + i * 16 + lm) * 64 + cpos];
#pragma unroll
                for (int j = 0; j < 4; ++j)
                    b[j] = *(const half8*)&sB[lo + (wn + j * 16 + lm) * 64 + cpos];
#pragma unroll
                for (int i = 0; i < 4; ++i)
#pragma unroll
                    for (int j = 0; j < 4; ++j)
                        acc[i][j] = __builtin_amdgcn_mfma_f32_16x16x32_f16(a[i], b[j], acc[i][j], 0, 0, 0);
            }
        }
    }
    const int region = N0 >> 8;               // 0..3 uniform per block (128|256)
    const int eobase = (N0 & 255) + wn;
    _Float16* basep = ((region & 1) == 0) ? xh : zh;
#pragma unroll
    for (int i = 0; i < 4; ++i) {
#pragma unroll
        for (int r = 0; r < 4; ++r) {
            int m = M0 + wm + i * 16 + q * 4 + r;
            int b = m >> 12, l = m & 4095;
            size_t rowoff = (region < 2)
                ? ((size_t)b * 4096 + l) * 256
                : ((size_t)(b + 2) * 4096 + (4095 - l)) * 256;
#pragma unroll
            for (int j = 0; j < 4; ++j)
                basep[rowoff + eobase + j * 16 + lm] = (_Float16)acc[i][j][r];
        }
    }
}

// ============================================================================
// out_proj: M=8192 (b,l), N=512 (o), K=1024. 128x64 tile (N=512 is
// parallelism-constrained), 4 waves each 64x32 (acc[4][2]). BK=128 via two
// slabs per barrier-pair: barrier-pairs 16 -> 8. LDS 48 KB; grid 512.
// ============================================================================
__global__ __launch_bounds__(256)
void k_out_proj_mfma(const _Float16* __restrict__ Af, const _Float16* __restrict__ Bf,
                     float* __restrict__ out)
{
    __shared__ _Float16 sA[2 * 128 * 64], sB[2 * 64 * 64];    // 32KB + 16KB
    const int K_ = 1024;
    const int t = threadIdx.x;
    const int wv = t >> 6, lane = t & 63;
    const int wm = (wv & 1) * 64, wn = (wv >> 1) * 32;
    const int lm = lane & 15, q = lane >> 4;
    const int M0 = (int)(blockIdx.x & 63) * 128;
    const int N0 = (int)(blockIdx.x >> 6) * 64;
    const int lr = lane >> 3;
    const int cc = (lane & 7) ^ lr;
    const size_t gA = (size_t)(M0 + wv * 32 + lr) * K_ + cc * 8;
    const size_t gB = (size_t)(N0 + wv * 16 + lr) * K_ + cc * 8;
    f32x4 acc[4][2] = {};
    for (int kb = 0; kb < K_; kb += 128) {
        __syncthreads();
#pragma unroll
        for (int s = 0; s < 2; ++s) {
            const int ko = kb + s * 64;
            const int loA = s * 8192, loB = s * 4096;
            gload16(Af + gA + ko,                   &sA[loA + (wv * 32 +  0) * 64]);
            gload16(Af + gA + (size_t)8  * K_ + ko, &sA[loA + (wv * 32 +  8) * 64]);
            gload16(Af + gA + (size_t)16 * K_ + ko, &sA[loA + (wv * 32 + 16) * 64]);
            gload16(Af + gA + (size_t)24 * K_ + ko, &sA[loA + (wv * 32 + 24) * 64]);
            gload16(Bf + gB + ko,                   &sB[loB + (wv * 16 +  0) * 64]);
            gload16(Bf + gB + (size_t)8  * K_ + ko, &sB[loB + (wv * 16 +  8) * 64]);
        }
        __syncthreads();
#pragma unroll
        for (int s = 0; s < 2; ++s) {
            const int loA = s * 8192, loB = s * 4096;
#pragma unroll
            for (int kk = 0; kk < 2; ++kk) {
                const int cpos = (((kk << 2) + q) ^ (lm & 7)) * 8;
                half8 a[4], b[2];
#pragma unroll
                for (int i = 0; i < 4; ++i)
                    a[i] = *(const half8*)&sA[loA + (wm + i * 16 + lm) * 64 + cpos];
#pragma unroll
                for (int j = 0; j < 2; ++j)
                    b[j] = *(const half8*)&sB[loB + (wn + j * 16 + lm) * 64 + cpos];
#pragma unroll
                for (int i = 0; i < 4; ++i)
#pragma unroll
                    for (int j = 0; j < 2; ++j)
                        acc[i][j] = __builtin_amdgcn_mfma_f32_16x16x32_f16(a[i], b[j], acc[i][j], 0, 0, 0);
            }
        }
    }
#pragma unroll
    for (int i = 0; i < 4; ++i) {
#pragma unroll
        for (int r = 0; r < 4; ++r) {
            size_t m = (size_t)(M0 + wm + i * 16 + q * 4 + r);
#pragma unroll
            for (int j = 0; j < 2; ++j)
                out[m * 512 + N0 + wn + j * 16 + lm] = acc[i][j][r];
        }
    }
}

// ============================================================================
// conv_x (dil 8 -> u fp16) and conv_z (dil 1 -> ybuf fp16, un-reversal folded)
// merged: fp16 in, fp32 math, fp16 out. 8 channels / thread (half8 = 16B).
// ============================================================================
__global__ __launch_bounds__(256)
void k_conv_both(const _Float16* __restrict__ xh, const _Float16* __restrict__ zh,
                 const float* __restrict__ wx, const float* __restrict__ wz,
                 _Float16* __restrict__ uh, _Float16* __restrict__ yb)
{
    int gid = blockIdx.x * 256 + threadIdx.x;
    const bool isZ = gid >= 524288;
    int idx = gid & 524287;
    int b = idx >> 17, rem = idx & 131071;
    int l = rem >> 5, d0 = (rem & 31) * 8;
    const _Float16* base = (isZ ? zh : xh) + (size_t)b * 4096 * 256 + d0;
    const float* w = (isZ ? wz : wx) + d0 * 4;
    const int dil = isZ ? 1 : 8;
    float wt[8][4];
#pragma unroll
    for (int j = 0; j < 8; ++j) {
        float4 wv = *(const float4*)(w + j * 4);
        wt[j][0] = wv.x; wt[j][1] = wv.y; wt[j][2] = wv.z; wt[j][3] = wv.w;
    }
    float acc[8];
    half8 v = *(const half8*)(base + (size_t)l * 256);
#pragma unroll
    for (int j = 0; j < 8; ++j) acc[j] = wt[j][3] * (float)v[j];
#pragma unroll
    for (int tp = 1; tp <= 3; ++tp) {
        int ls = l - tp * dil;
        if (ls >= 0) {
            half8 vv = *(const half8*)(base + (size_t)ls * 256);
#pragma unroll
            for (int j = 0; j < 8; ++j) acc[j] += wt[j][3 - tp] * (float)vv[j];
        }
    }
    half8 o;
#pragma unroll
    for (int j = 0; j < 8; ++j) o[j] = (_Float16)silu_f(acc[j]);
    if (!isZ) {
        *(half8*)(uh + ((size_t)b * 4096 + l) * 256 + d0) = o;
    } else {
        size_t oidx = (b < 2) ? ((size_t)b * 4096 + l) * 1024 + 256 + d0
                              : ((size_t)(b - 2) * 4096 + (4095 - l)) * 1024 + 768 + d0;
        *(half8*)(yb + oidx) = o;
    }
}

// ============================================================================
// x_proj as MFMA bt-GEMM: C[m][e] = sum_k u[m][k] Wx[e][k].
// M=16384, N=48, K=256. BM=64, full K staged at once, ONE barrier.
// ============================================================================
__global__ __launch_bounds__(256)
void k_xproj_mfma(const _Float16* __restrict__ Af, const _Float16* __restrict__ Bf,
                  float* __restrict__ xdbl)
{
    __shared__ _Float16 sA[4 * 64 * 64];   // 32KB: [slab][64 rows][64]
    __shared__ _Float16 sB[4 * 48 * 64];   // 24KB: [slab][48 rows][64]
    const int t = threadIdx.x;
    const int wv = t >> 6, lane = t & 63;
    const int lm = lane & 15, q = lane >> 4;
    const int lr = lane >> 3;
    const int cc = (lane & 7) ^ lr;        // swizzled source chunk
    const int m0 = blockIdx.x * 64;
    const size_t gA = (size_t)(m0 + wv * 16 + lr) * 256 + cc * 8;
    const size_t gB = (size_t)(wv * 16 + lr) * 256 + cc * 8;
#pragma unroll
    for (int s = 0; s < 4; ++s) {
        gload16(Af + gA + s * 64,                   &sA[s * 4096 + (wv * 16 + 0) * 64]);
        gload16(Af + gA + (size_t)8 * 256 + s * 64, &sA[s * 4096 + (wv * 16 + 8) * 64]);
        if (wv < 3) {
            gload16(Bf + gB + s * 64,                   &sB[s * 3072 + (wv * 16 + 0) * 64]);
            gload16(Bf + gB + (size_t)8 * 256 + s * 64, &sB[s * 3072 + (wv * 16 + 8) * 64]);
        }
    }
    __syncthreads();
    f32x4 acc[3] = {};
#pragma unroll
    for (int s = 0; s < 4; ++s) {
#pragma unroll
        for (int kk = 0; kk < 2; ++kk) {
            const int cpos = (((kk << 2) + q) ^ (lm & 7)) * 8;
            half8 a = *(const half8*)&sA[s * 4096 + (wv * 16 + lm) * 64 + cpos];
#pragma unroll
            for (int j = 0; j < 3; ++j) {
                half8 b = *(const half8*)&sB[s * 3072 + (j * 16 + lm) * 64 + cpos];
                acc[j] = __builtin_amdgcn_mfma_f32_16x16x32_f16(a, b, acc[j], 0, 0, 0);
            }
        }
    }
#pragma unroll
    for (int j = 0; j < 3; ++j)
#pragma unroll
        for (int r = 0; r < 4; ++r)
            xdbl[(size_t)(m0 + wv * 16 + q * 4 + r) * 48 + j * 16 + lm] = acc[j][r];
}

// ============================================================================
// Selective scan pass 1, chunked (NCHUNK=256 x CLEN=16). dt_proj fused.
// (Split kernels: round-6's cooperative fusion spilled to scratch at the
//  launch_bounds VGPR cap + double grid.sync -- 300us vs ~15us. Keep split.)
// ============================================================================
__global__ __launch_bounds__(256)
void k_scan1(const _Float16* __restrict__ uh, const float* __restrict__ xdbl,
             const float* __restrict__ WT, const float* __restrict__ bdt,
             const float* __restrict__ A_log,
             float* __restrict__ chS, float* __restrict__ chB)
{
    __shared__ float Xs[CLEN][36];
    __shared__ float Bsh[8][CLEN];
    const int b = blockIdx.x >> 8;
    const int c = blockIdx.x & 255;
    const int d = threadIdx.x;
    const int l0 = c * CLEN;
    const size_t mbase = (size_t)b * 4096 + l0;
    if (threadIdx.x < 128) {               // 16 rows x 32 dtr cols = 128 float4
        int r = threadIdx.x >> 3, cc = (threadIdx.x & 7) * 4;
        *(float4*)&Xs[r][cc] = *(const float4*)(xdbl + (mbase + r) * 48 + cc);
    } else {
        int s = threadIdx.x - 128;
        int i = s >> 3, n = s & 7;
        Bsh[n][i] = xdbl[(mbase + i) * 48 + 32 + n];
    }
    float w[32];
#pragma unroll
    for (int k = 0; k < 32; ++k) w[k] = WT[k * 256 + d];
    const float bias = bdt[d];
    float a[8], h[8];
#pragma unroll
    for (int n = 0; n < 8; ++n) { a[n] = -__expf(A_log[d * 8 + n]); h[n] = 0.0f; }
    float S = 0.0f;
    __syncthreads();
    const _Float16* up = uh + mbase * 256 + d;
    for (int i = 0; i < CLEN; ++i) {
        const float4* xr = (const float4*)&Xs[i][0];
        float accd = bias;
#pragma unroll
        for (int j = 0; j < 8; ++j) {
            float4 xv = xr[j];
            accd = fmaf(xv.x, w[4*j+0], accd);
            accd = fmaf(xv.y, w[4*j+1], accd);
            accd = fmaf(xv.z, w[4*j+2], accd);
            accd = fmaf(xv.w, w[4*j+3], accd);
        }
        float dlt = softplus_f(accd);
        float u   = (float)up[(size_t)i * 256];
        float du  = dlt * u;
        S += dlt;
#pragma unroll
        for (int n = 0; n < 8; ++n) {
            float dA = __expf(dlt * a[n]);
            h[n] = dA * h[n] + du * Bsh[n][i];
        }
    }
    chS[((size_t)b * NCHUNK + c) * 256 + d] = S;
#pragma unroll
    for (int n = 0; n < 8; ++n)
        chB[(((size_t)b * NCHUNK + c) * 8 + n) * 256 + d] = h[n];
}

// ============================================================================
// Hierarchical inter-chunk scan, level 1: 256 blocks (b,n,seg), 32 serial
// steps each. Stores exclusive within-seg prefixes + segment aggregates.
// ============================================================================
__global__ __launch_bounds__(256)
void k_scan2a(const float* __restrict__ chS, const float* __restrict__ chB,
              const float* __restrict__ A_log,
              float* __restrict__ hloc, float* __restrict__ scum,
              float* __restrict__ segS, float* __restrict__ segB)
{
    const int b   = blockIdx.x >> 6;
    const int n   = (blockIdx.x >> 3) & 7;
    const int seg = blockIdx.x & 7;
    const int d   = threadIdx.x;
    const int c0  = seg * SEGC;
    const float a = -__expf(A_log[d * 8 + n]);
    float h = 0.0f, Sc = 0.0f;
    for (int jb = 0; jb < SEGC; jb += 16) {
        float S[16], Bc[16];
#pragma unroll
        for (int j = 0; j < 16; ++j) {
            int c = c0 + jb + j;
            S[j]  = chS[((size_t)b * NCHUNK + c) * 256 + d];
            Bc[j] = chB[(((size_t)b * NCHUNK + c) * 8 + n) * 256 + d];
        }
#pragma unroll
        for (int j = 0; j < 16; ++j) {
            int c = c0 + jb + j;
            hloc[(((size_t)b * NCHUNK + c) * 8 + n) * 256 + d] = h;
            if (n == 0) scum[((size_t)b * NCHUNK + c) * 256 + d] = Sc;
            h  = __expf(a * S[j]) * h + Bc[j];
            Sc += S[j];
        }
    }
    segB[(((size_t)b * NSEG + seg) * 8 + n) * 256 + d] = h;
    if (n == 0) segS[((size_t)b * NSEG + seg) * 256 + d] = Sc;
}

// ============================================================================
// Selective scan pass 2 (+ cross-segment compose prologue + dt_proj fused).
// ============================================================================
__global__ __launch_bounds__(256)
void k_scan3(const _Float16* __restrict__ uh, const float* __restrict__ xdbl,
             const float* __restrict__ WT, const float* __restrict__ bdt,
             const float* __restrict__ A_log, const float* __restrict__ Dp,
             const float* __restrict__ hloc, const float* __restrict__ scum,
             const float* __restrict__ segS, const float* __restrict__ segB,
             _Float16* __restrict__ yb)
{
    __shared__ float Xs[CLEN][36];
    __shared__ float Bsh[8][CLEN];
    __shared__ float Csh[8][CLEN];
    const int b = blockIdx.x >> 8;
    const int c = blockIdx.x & 255;
    const int seg = c >> 5;                // segment of this chunk
    const int d = threadIdx.x;
    const int l0 = c * CLEN;
    const size_t mbase = (size_t)b * 4096 + l0;
    if (threadIdx.x < 128) {
        int r = threadIdx.x >> 3, cc = (threadIdx.x & 7) * 4;
        *(float4*)&Xs[r][cc] = *(const float4*)(xdbl + (mbase + r) * 48 + cc);
    } else {
        int s = threadIdx.x - 128;
        int i = s >> 3, n = s & 7;
        Bsh[n][i] = xdbl[(mbase + i) * 48 + 32 + n];
        Csh[n][i] = xdbl[(mbase + i) * 48 + 40 + n];
    }
    float w[32];
#pragma unroll
    for (int k = 0; k < 32; ++k) w[k] = WT[k * 256 + d];
    const float bias = bdt[d];
    float a[8];
#pragma unroll
    for (int n = 0; n < 8; ++n) a[n] = -__expf(A_log[d * 8 + n]);
    // cross-segment compose: h at segment start (seg is block-uniform)
    float hs_[8];
#pragma unroll
    for (int n = 0; n < 8; ++n) hs_[n] = 0.0f;
    for (int s = 0; s < seg; ++s) {
        float Es = segS[((size_t)b * NSEG + s) * 256 + d];
#pragma unroll
        for (int n = 0; n < 8; ++n)
            hs_[n] = __expf(a[n] * Es) * hs_[n]
                   + segB[(((size_t)b * NSEG + s) * 8 + n) * 256 + d];
    }
    // h at chunk start
    const float Sc = scum[((size_t)b * NCHUNK + c) * 256 + d];
    float h[8];
#pragma unroll
    for (int n = 0; n < 8; ++n)
        h[n] = __expf(a[n] * Sc) * hs_[n]
             + hloc[(((size_t)b * NCHUNK + c) * 8 + n) * 256 + d];
    const float Dd = Dp[d];
    __syncthreads();
    const _Float16* up = uh + mbase * 256 + d;
    for (int i = 0; i < CLEN; ++i) {
        const float4* xr = (const float4*)&Xs[i][0];
        float accd = bias;
#pragma unroll
        for (int j = 0; j < 8; ++j) {
            float4 xv = xr[j];
            accd = fmaf(xv.x, w[4*j+0], accd);
            accd = fmaf(xv.y, w[4*j+1], accd);
            accd = fmaf(xv.z, w[4*j+2], accd);
            accd = fmaf(xv.w, w[4*j+3], accd);
        }
        float dlt = softplus_f(accd);
        float u   = (float)up[(size_t)i * 256];
        float du  = dlt * u;
        float y   = u * Dd;
#pragma unroll
        for (int n = 0; n < 8; ++n) {
            float dA = __expf(dlt * a[n]);
            h[n] = dA * h[n] + du * Bsh[n][i];
            y += h[n] * Csh[n][i];
        }
        int l = l0 + i;
        size_t oidx = (b < 2) ? ((size_t)b * 4096 + l) * 1024 + d
                              : ((size_t)(b - 2) * 4096 + (4095 - l)) * 1024 + 512 + d;
        yb[oidx] = (_Float16)y;
    }
}

// ============================================================================
extern "C" void kernel_launch(void* const* d_in, const int* in_sizes, int n_in,
                              void* d_out, int out_size, void* d_ws, size_t ws_size,
                              hipStream_t stream)
{
    const float* hs    = (const float*)d_in[0];   // (2,4096,512)
    const float* w_in  = (const float*)d_in[1];   // (1024,512)
    const float* w_xp  = (const float*)d_in[2];   // (48,256)
    const float* w_dt  = (const float*)d_in[3];   // (256,32)
    const float* b_dt  = (const float*)d_in[4];   // (256,)
    const float* A_log = (const float*)d_in[5];   // (256,8)
    const float* Dpar  = (const float*)d_in[6];   // (256,)
    const float* w_cx  = (const float*)d_in[7];   // (256,1,4)
    const float* w_cz  = (const float*)d_in[8];   // (256,1,4)
    const float* w_out = (const float*)d_in[9];   // (512,1024)
    float* out = (float*)d_out;                   // (2,4096,512)

    float* ws   = (float*)d_ws;
    float*    xdbl = ws;                            // [4][4096][48]          786432 f
    float*    chS  = xdbl + 786432;                 // [4][256][256]          262144 f
    float*    chB  = chS  + 262144;                 // [4][256][8][256]      2097152 f
    float*    hloc = chB  + 2097152;                // [4][256][8][256]      2097152 f
    float*    scum = hloc + 2097152;                // [4][256][256]          262144 f
    float*    segS = scum + 262144;                 // [4][8][256]              8192 f
    float*    segB = segS + 8192;                   // [4][8][8][256]          65536 f
    float*    wtT  = segB + 65536;                  // [32][256] Wdt^T          8192 f
    _Float16* xh   = (_Float16*)(wtT + 8192);       // [4][4096][256] fp16
    _Float16* zh   = xh + 4194304;                  // [4][4096][256] fp16
    _Float16* uh   = zh + 4194304;                  // [4][4096][256] fp16
    _Float16* hsf  = uh + 4194304;                  // [8192][512] fp16
    _Float16* wif  = hsf + 4194304;                 // [1024][512] fp16
    _Float16* wof  = wif + 524288;                  // [512][1024] fp16
    _Float16* wxh  = wof + 524288;                  // [48][256] fp16
    _Float16* ybf  = wxh + 12288;                   // [2][4096][1024] fp16

    k_cast_all     <<<5200, 256, 0, stream>>>(hs, hsf, w_in, wif, w_out, wof,
                                              w_dt, wtT, w_xp, wxh);
    k_in_proj_mfma <<<512,  256, 0, stream>>>(hsf, wif, xh, zh);
    k_conv_both    <<<4096, 256, 0, stream>>>(xh, zh, w_cx, w_cz, uh, ybf);
    k_xproj_mfma   <<<256,  256, 0, stream>>>(uh, wxh, xdbl);
    k_scan1        <<<1024, 256, 0, stream>>>(uh, xdbl, wtT, b_dt, A_log, chS, chB);
    k_scan2a       <<<256,  256, 0, stream>>>(chS, chB, A_log, hloc, scum, segS, segB);
    k_scan3        <<<1024, 256, 0, stream>>>(uh, xdbl, wtT, b_dt, A_log, Dpar,
                                              hloc, scum, segS, segB, ybf);
    k_out_proj_mfma<<<512,  256, 0, stream>>>(ybf, wof, out);
}